// Round 3
// baseline (184.425 us; speedup 1.0000x reference)
//
#include <hip/hip_runtime.h>
#include <cmath>

// PillarFeatureNet fused: augment(10ch) -> linear(64) -> BN -> exact GELU -> max over points.
// R1 55.4us / R2 57us: DS-pipe-bound. lane=channel requires broadcasting every point to all
// 64 lanes; ds_read broadcast still returns 64x16B=1KB through the 128B/clk DS bus
// (~3.2M DS ops ~= 42us pipe occupancy). VALU cut in R2 changed nothing -> DS was the bound.
// R3: move the broadcast to the SCALAR path. Pillar addresses are wave-uniform, so point
// data goes into SGPRs via s_load_dwordx16 (inline asm). SGPR operands are free broadcasts:
// inner loop = v_fma_f32 v,s,v,v. ZERO LDS. One pillar per wave-iteration, 8-pt chunks
// (32 data SGPRs live). Sums over ALL 32 raw rows (ref semantics) as SGPR-sourced trees;
// dot/minmax only on valid chunks (wave-uniform scalar branch); boundary chunk neutralized
// with point-0 copies via scalar cselect (free pipe). C folded after minmax:
// max_m(dot_m + C) = max_m(dot_m) + C. GELU valley: 2 erfs per (pillar,channel).

typedef float v16f __attribute__((ext_vector_type(16)));
typedef int   v4i  __attribute__((ext_vector_type(4)));

__device__ __forceinline__ float gelu_exact(float x) {
    return 0.5f * x * (1.0f + erff(x * 0.70710678118654752440f));
}

__device__ __forceinline__ float dotp(float x, float y, float z, float w,
                                      float A0, float A1, float A2, float A3) {
    // v_fma_f32 with one SGPR source each: 4 VALU
    return fmaf(x, A0, fmaf(y, A1, fmaf(z, A2, w * A3)));
}

struct Acc { float sx, sy, sz, mx, mn; };

// u0 = points base..base+3, u1 = base+4..base+7, interleaved [x y z w] per point.
__device__ __forceinline__ void proc_chunk(const v16f u0, const v16f u1, int base, int ns,
                                           float x0, float y0, float z0, float w0,
                                           float A0, float A1, float A2, float A3, Acc& ac)
{
    // xyz sums over ALL 8 raw points (tree for ILP); reference sums all 32 rows.
    ac.sx += ((u0[0] + u0[4]) + (u0[8] + u0[12])) + ((u1[0] + u1[4]) + (u1[8] + u1[12]));
    ac.sy += ((u0[1] + u0[5]) + (u0[9] + u0[13])) + ((u1[1] + u1[5]) + (u1[9] + u1[13]));
    ac.sz += ((u0[2] + u0[6]) + (u0[10] + u0[14])) + ((u1[2] + u1[6]) + (u1[10] + u1[14]));

    if (ns >= base + 8) {           // fully valid chunk (wave-uniform branch)
        float p0 = dotp(u0[0],  u0[1],  u0[2],  u0[3],  A0, A1, A2, A3);
        float p1 = dotp(u0[4],  u0[5],  u0[6],  u0[7],  A0, A1, A2, A3);
        float p2 = dotp(u0[8],  u0[9],  u0[10], u0[11], A0, A1, A2, A3);
        float p3 = dotp(u0[12], u0[13], u0[14], u0[15], A0, A1, A2, A3);
        float p4 = dotp(u1[0],  u1[1],  u1[2],  u1[3],  A0, A1, A2, A3);
        float p5 = dotp(u1[4],  u1[5],  u1[6],  u1[7],  A0, A1, A2, A3);
        float p6 = dotp(u1[8],  u1[9],  u1[10], u1[11], A0, A1, A2, A3);
        float p7 = dotp(u1[12], u1[13], u1[14], u1[15], A0, A1, A2, A3);
        // fmax(fmax(a,b),acc) folds to v_max3: ~1 op per point for minmax
        ac.mx = fmaxf(fmaxf(p6, p7), fmaxf(fmaxf(p4, p5),
                fmaxf(fmaxf(p2, p3), fmaxf(fmaxf(p0, p1), ac.mx))));
        ac.mn = fminf(fminf(p6, p7), fminf(fminf(p4, p5),
                fminf(fminf(p2, p3), fminf(fminf(p0, p1), ac.mn))));
    } else if (ns > base) {         // boundary chunk: neutralize invalid pts with pt0 (scalar cselects)
        #define DOTSEL(u, j)                                                     \
            { bool vld = (base + (j)) < ns;                                      \
              float xs_ = vld ? u[4*(j)+0] : x0;                                 \
              float ys_ = vld ? u[4*(j)+1] : y0;                                 \
              float zs_ = vld ? u[4*(j)+2] : z0;                                 \
              float ws_ = vld ? u[4*(j)+3] : w0;                                 \
              float pv  = dotp(xs_, ys_, zs_, ws_, A0, A1, A2, A3);              \
              ac.mx = fmaxf(ac.mx, pv); ac.mn = fminf(ac.mn, pv); }
        DOTSEL(u0, 0) DOTSEL(u0, 1) DOTSEL(u0, 2) DOTSEL(u0, 3)
        DOTSEL(u1, 0) DOTSEL(u1, 1) DOTSEL(u1, 2) DOTSEL(u1, 3)
        #undef DOTSEL
    }
}

__global__ __launch_bounds__(256) void pfn_kernel(
    const float* __restrict__ features,   // (N, 32, 4)
    const int*   __restrict__ num_points, // (N,)
    const int*   __restrict__ coors,      // (N, 4)
    const float* __restrict__ W,          // (64, 10)
    const float* __restrict__ gamma,
    const float* __restrict__ beta,
    const float* __restrict__ rmean,
    const float* __restrict__ rvar,
    float*       __restrict__ out,        // (N, 64)
    int nTotal)
{
    // force wave-id uniform so downstream pointers are provably uniform for "s" constraints
    const int wid = __builtin_amdgcn_readfirstlane(threadIdx.x) >> 6;
    const int waveGlobal = blockIdx.x * 4 + wid;
    const int waveCount  = gridDim.x * 4;

    const int o = threadIdx.x & 63;       // lane == output channel
    const float w0 = W[o*10+0], w1 = W[o*10+1], w2 = W[o*10+2], w3 = W[o*10+3],
                w4 = W[o*10+4], w5 = W[o*10+5], w6 = W[o*10+6], w7 = W[o*10+7],
                w8 = W[o*10+8], w9 = W[o*10+9];
    const float a = gamma[o] / sqrtf(rvar[o] + 1e-3f);
    const float b = fmaf(-rmean[o], a, beta[o]);        // BN(0): masked rows' y
    const float A0 = a*(w0+w4+w7), A1 = a*(w1+w5+w8), A2 = a*(w2+w6+w9), A3 = a*w3;

    for (int i = waveGlobal; i < nTotal; i += waveCount) {
        const float* fptr = features + (size_t)i * 128;

        int ns; v4i cr; v16f u0, u1;
        // chunk 0 (+ num_points + coors) straight into SGPRs; early-clobber so
        // outputs never alias the base-pointer inputs while loads are in flight.
        asm volatile(
            "s_load_dword %0, %4, 0x0\n\t"
            "s_load_dwordx4 %1, %5, 0x0\n\t"
            "s_load_dwordx16 %2, %6, 0x0\n\t"
            "s_load_dwordx16 %3, %6, 0x40\n\t"
            "s_waitcnt lgkmcnt(0)"
            : "=&s"(ns), "=&s"(cr), "=&s"(u0), "=&s"(u1)
            : "s"(num_points + i), "s"(coors + (size_t)4 * i), "s"(fptr));

        const float x0 = u0[0], y0 = u0[1], z0 = u0[2], w0p = u0[3];  // neutral fill (pt0 always valid)
        Acc ac = { 0.f, 0.f, 0.f, -INFINITY, INFINITY };

        proc_chunk(u0, u1, 0, ns, x0, y0, z0, w0p, A0, A1, A2, A3, ac);

        asm volatile(
            "s_load_dwordx16 %0, %2, 0x80\n\t"
            "s_load_dwordx16 %1, %2, 0xC0\n\t"
            "s_waitcnt lgkmcnt(0)"
            : "=&s"(u0), "=&s"(u1) : "s"(fptr));
        proc_chunk(u0, u1, 8, ns, x0, y0, z0, w0p, A0, A1, A2, A3, ac);

        asm volatile(
            "s_load_dwordx16 %0, %2, 0x100\n\t"
            "s_load_dwordx16 %1, %2, 0x140\n\t"
            "s_waitcnt lgkmcnt(0)"
            : "=&s"(u0), "=&s"(u1) : "s"(fptr));
        proc_chunk(u0, u1, 16, ns, x0, y0, z0, w0p, A0, A1, A2, A3, ac);

        asm volatile(
            "s_load_dwordx16 %0, %2, 0x180\n\t"
            "s_load_dwordx16 %1, %2, 0x1C0\n\t"
            "s_waitcnt lgkmcnt(0)"
            : "=&s"(u0), "=&s"(u1) : "s"(fptr));
        proc_chunk(u0, u1, 24, ns, x0, y0, z0, w0p, A0, A1, A2, A3, ac);

        // ---- epilogue: fold mean/coors constant, BN, gelu-valley, store ----
        const float rc = __builtin_amdgcn_rcpf((float)ns);   // ~1ulp, fine at tolerance
        const float mx_ = ac.sx * rc, my_ = ac.sy * rc, mz_ = ac.sz * rc;
        const float ccx = fmaf((float)cr[2], 0.2f,   0.1f);  // cx = coors[:,2]
        const float ccy = fmaf((float)cr[1], 0.2f, -39.9f);  // cy = coors[:,1]
        const float ccz = fmaf((float)cr[0], 4.0f,  -1.0f);  // cz = coors[:,0]
        const float K = -fmaf(mx_, w4, fmaf(my_, w5, fmaf(mz_, w6,
                         fmaf(ccx, w7, fmaf(ccy, w8, ccz * w9)))));
        const float C = fmaf(a, K, b);

        float ymax = ac.mx + C, ymin = ac.mn + C;
        if (ns < 32) { ymax = fmaxf(ymax, b); ymin = fminf(ymin, b); }  // masked rows -> BN(0)

        const float r = fmaxf(gelu_exact(ymax), gelu_exact(ymin));
        out[(size_t)i * 64 + o] = r;
    }
}

extern "C" void kernel_launch(void* const* d_in, const int* in_sizes, int n_in,
                              void* d_out, int out_size, void* d_ws, size_t ws_size,
                              hipStream_t stream) {
    const float* features   = (const float*)d_in[0];
    const int*   num_points = (const int*)  d_in[1];
    const int*   coors      = (const int*)  d_in[2];
    const float* W          = (const float*)d_in[3];
    const float* gamma      = (const float*)d_in[4];
    const float* beta       = (const float*)d_in[5];
    const float* rmean      = (const float*)d_in[6];
    const float* rvar       = (const float*)d_in[7];
    float* out = (float*)d_out;

    const int nTotal = in_sizes[1];  // N pillars

    // 2048 blocks x 4 waves = 8192 waves = 32 waves/CU; ~12 pillars per wave
    pfn_kernel<<<2048, 256, 0, stream>>>(features, num_points, coors, W,
                                         gamma, beta, rmean, rvar, out, nTotal);
}

// Round 6
// 137.228 us; speedup vs baseline: 1.3439x; 1.3439x over previous
//
#include <hip/hip_runtime.h>
#include <cmath>

// PillarFeatureNet fused: augment(10ch) -> linear(64) -> BN -> exact GELU -> max over points.
// R1 55us / R2 57us: DS-broadcast-bound (64-lane broadcast through 128B/clk DS bus).
// R3 107us: SGPR broadcast right for dots, but xyz sums on SGPRs = wave-redundant VALU
// storms (no scalar FP ALU) + 4 serialized lgkm drains.
// R4: DPP-tree sums on the vector pipe + batched drains.  (compile fail: DPP ctrl imm)
// R5: template-param DPP ctrl.  (compile fail: 69 early-clobber SGPR outs in ONE asm
//     blew the allocator)
// R6: same structure, asm split into <=32-SGPR-output statements; issue all phase loads,
// single lgkmcnt(0) drain tying values. Peak live SGPR ~85/102 -- allocatable.
// Mean sums ALL 32 raw rows (ref semantics); mask gates only the matmul (masked rows ->
// y = BN(0) = b, folded once). C folded post-minmax: max_m(dot+C) = max(dot)+C.
// GELU valley-shaped: max over set = max(gelu(ymin), gelu(ymax)) -> 2 erfs/(pillar,ch).

typedef float v16f __attribute__((ext_vector_type(16)));
typedef int   v4i  __attribute__((ext_vector_type(4)));

__device__ __forceinline__ float gelu_exact(float x) {
    return 0.5f * x * (1.0f + erff(x * 0.70710678118654752440f));
}

template <int CTRL>
__device__ __forceinline__ float dpp_add(float v) {
    int t = __builtin_amdgcn_update_dpp(0, __float_as_int(v), CTRL, 0xf, 0xf, true);
    return v + __int_as_float(t);
}

// Sum lanes 0..31: row_shl 1,2,4,8 -> lane15/31 hold row sums; row_bcast15 adds
// lane15 into row1 -> lane31 = 32-lane sum. All VALU pipe, zero DS traffic.
__device__ __forceinline__ float half_sum32(float x) {
    x = dpp_add<0x101>(x);   // row_shl:1
    x = dpp_add<0x102>(x);   // row_shl:2
    x = dpp_add<0x104>(x);   // row_shl:4
    x = dpp_add<0x108>(x);   // row_shl:8
    x = dpp_add<0x142>(x);   // row_bcast:15
    return __int_as_float(__builtin_amdgcn_readlane(__float_as_int(x), 31));
}

// One dwordx16 = 4 points [x y z w]*4 in SGPRs. Uniform branches; boundary fill from the
// chunk's own point BASE (valid because ns > BASE) via s_cselect (SALU pipe, free).
#define CHUNK4(U, BASE)                                                              \
  if (ns > (BASE)) {                                                                 \
    float xs0,ys0,zs0,ws0,xs1,ys1,zs1,ws1,xs2,ys2,zs2,ws2,xs3,ys3,zs3,ws3;           \
    xs0=U[0]; ys0=U[1]; zs0=U[2]; ws0=U[3];                                          \
    if (ns >= (BASE)+4) {                                                            \
      xs1=U[4]; ys1=U[5]; zs1=U[6];  ws1=U[7];                                       \
      xs2=U[8]; ys2=U[9]; zs2=U[10]; ws2=U[11];                                      \
      xs3=U[12];ys3=U[13];zs3=U[14]; ws3=U[15];                                      \
    } else {                                                                         \
      bool v1=(BASE)+1<ns, v2=(BASE)+2<ns, v3=(BASE)+3<ns;                           \
      xs1=v1?U[4]:xs0;  ys1=v1?U[5]:ys0;  zs1=v1?U[6]:zs0;  ws1=v1?U[7]:ws0;         \
      xs2=v2?U[8]:xs0;  ys2=v2?U[9]:ys0;  zs2=v2?U[10]:zs0; ws2=v2?U[11]:ws0;        \
      xs3=v3?U[12]:xs0; ys3=v3?U[13]:ys0; zs3=v3?U[14]:zs0; ws3=v3?U[15]:ws0;        \
    }                                                                                \
    float d0 = fmaf(xs0,A0, fmaf(ys0,A1, fmaf(zs0,A2, ws0*A3)));                     \
    float d1 = fmaf(xs1,A0, fmaf(ys1,A1, fmaf(zs1,A2, ws1*A3)));                     \
    float d2 = fmaf(xs2,A0, fmaf(ys2,A1, fmaf(zs2,A2, ws2*A3)));                     \
    float d3 = fmaf(xs3,A0, fmaf(ys3,A1, fmaf(zs3,A2, ws3*A3)));                     \
    mxv = fmaxf(fmaxf(d0,d1), fmaxf(fmaxf(d2,d3), mxv));                             \
    mnv = fminf(fminf(d0,d1), fminf(fminf(d2,d3), mnv));                             \
  }

__global__ __launch_bounds__(256, 8) void pfn_kernel(
    const float* __restrict__ features,   // (N, 32, 4)
    const int*   __restrict__ num_points, // (N,)
    const int*   __restrict__ coors,      // (N, 4)
    const float* __restrict__ W,          // (64, 10)
    const float* __restrict__ gamma,
    const float* __restrict__ beta,
    const float* __restrict__ rmean,
    const float* __restrict__ rvar,
    float*       __restrict__ out,        // (N, 64)
    int nTotal)
{
    const int lane = threadIdx.x & 63;
    const int wid  = __builtin_amdgcn_readfirstlane(threadIdx.x) >> 6;
    const int waveGlobal = blockIdx.x * 4 + wid;
    const int waveCount  = gridDim.x * 4;

    const int o = lane;                  // lane == output channel
    const float w4 = W[o*10+4], w5 = W[o*10+5], w6 = W[o*10+6],
                w7 = W[o*10+7], w8 = W[o*10+8], w9 = W[o*10+9];
    const float a = gamma[o] / sqrtf(rvar[o] + 1e-3f);
    const float b = fmaf(-rmean[o], a, beta[o]);          // BN(0): masked rows' y
    const float A0 = a*(W[o*10+0]+w4+w7), A1 = a*(W[o*10+1]+w5+w8),
                A2 = a*(W[o*10+2]+w6+w9), A3 = a*W[o*10+3];

    for (int i = waveGlobal; i < nTotal; i += waveCount) {
        const float* fp = features + (size_t)i * 128;

        int ns; v4i cr; v16f u0, u1, u2, u3;
        // Issue phase-1 scalar loads in SMALL asm statements (<=32 SGPR outs each;
        // one 69-out statement broke the register allocator in R5). No waits yet.
        asm volatile(
            "s_load_dword %0, %3, 0x0\n\t"
            "s_load_dwordx4 %1, %4, 0x0\n\t"
            "s_load_dwordx16 %2, %5, 0x0"
            : "=&s"(ns), "=&s"(cr), "=&s"(u0)
            : "s"(num_points + i), "s"(coors + (size_t)4 * i), "s"(fp));
        asm volatile(
            "s_load_dwordx16 %0, %2, 0x40\n\t"
            "s_load_dwordx16 %1, %2, 0x80"
            : "=&s"(u1), "=&s"(u2) : "s"(fp));
        asm volatile(
            "s_load_dwordx16 %0, %1, 0xC0"
            : "=&s"(u3) : "s"(fp));

        // Vector path under SMEM latency: coalesced re-read of the same lines (L2-hit)
        // for the all-32-row xyz sums via DPP tree (VALU pipe only, no DS).
        const float4 f = reinterpret_cast<const float4*>(fp)[lane & 31];
        const float sx = half_sum32(f.x);
        const float sy = half_sum32(f.y);
        const float sz = half_sum32(f.z);

        // Single drain for all phase-1 SMEM (s_load returns may complete out-of-order);
        // "+s" ties force consumption to stay after the wait.
        asm volatile("s_waitcnt lgkmcnt(0)"
                     : "+s"(ns), "+s"(cr), "+s"(u0), "+s"(u1), "+s"(u2), "+s"(u3));

        float mxv = -INFINITY, mnv = INFINITY;
        CHUNK4(u0, 0) CHUNK4(u1, 4) CHUNK4(u2, 8) CHUNK4(u3, 12)

        if (ns > 16) {   // phase 2: pts 16..31 (uniform branch; ~50% of pillars skip)
            v16f t0, t1, t2, t3;   // fresh vars; u0..u3 dead -> allocator reuses
            asm volatile(
                "s_load_dwordx16 %0, %2, 0x100\n\t"
                "s_load_dwordx16 %1, %2, 0x140"
                : "=&s"(t0), "=&s"(t1) : "s"(fp));
            asm volatile(
                "s_load_dwordx16 %0, %2, 0x180\n\t"
                "s_load_dwordx16 %1, %2, 0x1C0"
                : "=&s"(t2), "=&s"(t3) : "s"(fp));
            asm volatile("s_waitcnt lgkmcnt(0)"
                         : "+s"(t0), "+s"(t1), "+s"(t2), "+s"(t3));
            CHUNK4(t0, 16) CHUNK4(t1, 20) CHUNK4(t2, 24) CHUNK4(t3, 28)
        }

        // ---- epilogue: fold mean/voxel-center constant, BN, gelu-valley, store ----
        const float rc  = __builtin_amdgcn_rcpf((float)ns);   // ~1ulp
        const float mx_ = sx * rc, my_ = sy * rc, mz_ = sz * rc;
        const float ccx = fmaf((float)cr[2], 0.2f,   0.1f);   // cx = coors[:,2]
        const float ccy = fmaf((float)cr[1], 0.2f, -39.9f);   // cy = coors[:,1]
        const float ccz = fmaf((float)cr[0], 4.0f,  -1.0f);   // cz = coors[:,0]
        const float K = -fmaf(mx_, w4, fmaf(my_, w5, fmaf(mz_, w6,
                         fmaf(ccx, w7, fmaf(ccy, w8, ccz * w9)))));
        const float C = fmaf(a, K, b);

        float ymax = mxv + C, ymin = mnv + C;
        if (ns < 32) { ymax = fmaxf(ymax, b); ymin = fminf(ymin, b); }

        out[(size_t)i * 64 + o] = fmaxf(gelu_exact(ymax), gelu_exact(ymin));
    }
}

extern "C" void kernel_launch(void* const* d_in, const int* in_sizes, int n_in,
                              void* d_out, int out_size, void* d_ws, size_t ws_size,
                              hipStream_t stream) {
    const float* features   = (const float*)d_in[0];
    const int*   num_points = (const int*)  d_in[1];
    const int*   coors      = (const int*)  d_in[2];
    const float* W          = (const float*)d_in[3];
    const float* gamma      = (const float*)d_in[4];
    const float* beta       = (const float*)d_in[5];
    const float* rmean      = (const float*)d_in[6];
    const float* rvar       = (const float*)d_in[7];
    float* out = (float*)d_out;

    const int nTotal = in_sizes[1];  // N pillars

    // 4096 blocks x 4 waves = 16384 waves = 2x wave capacity, ~6 pillars/wave
    pfn_kernel<<<4096, 256, 0, stream>>>(features, num_points, coors, W,
                                         gamma, beta, rmean, rvar, out, nTotal);
}